// Round 16
// baseline (324.659 us; speedup 1.0000x reference)
//
#include <hip/hip_runtime.h>

#define H 1024
#define UNITS 1024
#define BATCH 32
#define SEQ 2048
#define M_TOT (BATCH * SEQ)  // 65536

typedef __attribute__((ext_vector_type(8))) short bf16x8;
typedef __attribute__((ext_vector_type(8))) unsigned short u16x8;
typedef __attribute__((ext_vector_type(4))) float f32x4;

__device__ __forceinline__ unsigned short f2bf(float f) {
  union { float f; unsigned u; } x; x.f = f;
  unsigned r = x.u + 0x7FFFu + ((x.u >> 16) & 1u);  // RTN-even
  return (unsigned short)(r >> 16);
}
__device__ __forceinline__ float bf2f(unsigned short h) {
  union { unsigned u; float f; } x; x.u = (unsigned)h << 16;
  return x.f;
}

// async global->LDS, 16B per lane; LDS dest = wave-uniform base + lane*16
__device__ __forceinline__ void gll16(const unsigned short* g, unsigned short* l) {
  __builtin_amdgcn_global_load_lds(
      (const __attribute__((address_space(1))) void*)g,
      (__attribute__((address_space(3))) void*)l, 16, 0, 0);
}

// ---- fused prep: values cast (0..2047) + W1 transpose (2048..3071) +
//      projq (3072..3199) + scores/ctx zero-fill (3200..3231).
//      Replaces 3 kernels + 2 memsets with ONE dispatch (graph-gap trim).
__global__ void k_prep(const float* __restrict__ values, unsigned short* __restrict__ Vb,
                       const float* __restrict__ W1, unsigned short* __restrict__ W1T,
                       const float* __restrict__ query, const float* __restrict__ W2,
                       const float* __restrict__ b2, float* __restrict__ projq,
                       float* __restrict__ scores, float* __restrict__ ctx) {
  __shared__ float sh[1056];  // aliased: tile[32][33] (4224B) / q[1024] (4096B)
  const int blk = blockIdx.x;
  const int tid = threadIdx.x;
  if (blk < 2048) {
    for (int u = blk; u < 32768; u += 2048) {
      size_t i = ((size_t)u * 256 + tid) * 8;
      float4 v0 = *reinterpret_cast<const float4*>(values + i);
      float4 v1 = *reinterpret_cast<const float4*>(values + i + 4);
      union { unsigned short h[8]; u16x8 v; } p;
      p.h[0] = f2bf(v0.x); p.h[1] = f2bf(v0.y); p.h[2] = f2bf(v0.z); p.h[3] = f2bf(v0.w);
      p.h[4] = f2bf(v1.x); p.h[5] = f2bf(v1.y); p.h[6] = f2bf(v1.z); p.h[7] = f2bf(v1.w);
      *reinterpret_cast<u16x8*>(Vb + i) = p.v;
    }
  } else if (blk < 3072) {
    float (*tile)[33] = reinterpret_cast<float(*)[33]>(sh);
    const int t = blk - 2048;
    const int bx = t & 31, by = t >> 5;
    const int tx = tid & 31, ty = tid >> 5;  // 32 x 8
#pragma unroll
    for (int i = 0; i < 4; ++i)
      tile[ty + i * 8][tx] = W1[(by * 32 + ty + i * 8) * UNITS + bx * 32 + tx];
    __syncthreads();
#pragma unroll
    for (int i = 0; i < 4; ++i)
      W1T[(bx * 32 + ty + i * 8) * H + by * 32 + tx] = f2bf(tile[tx][ty + i * 8]);
  } else if (blk < 3200) {
    float* q = sh;
    const int t = blk - 3072;       // 0..127
    const int b = t >> 2;
    const int u = (t & 3) * 256 + tid;
    for (int i = tid; i < H; i += 256) q[i] = query[b * H + i];
    __syncthreads();
    float acc = 0.f;
#pragma unroll 8
    for (int k = 0; k < H; ++k) acc = fmaf(q[k], W2[k * UNITS + u], acc);
    projq[b * UNITS + u] = acc + b2[u];
  } else {
    // zero-fill: scores (65536 f32) + ctx (32768 f32); 32 blocks x 256 thr
    const int idx = (blk - 3200) * 256 + tid;  // 0..8191
    float4 z = make_float4(0.f, 0.f, 0.f, 0.f);
    *reinterpret_cast<float4*>(scores + idx * 8) = z;
    *reinterpret_cast<float4*>(scores + idx * 8 + 4) = z;
    *reinterpret_cast<float4*>(ctx + idx * 4) = z;
  }
}

// ============ 256x256 fused GEMM + tanh + dot(V) -> scores ===================
// R8's kernel — the measured family optimum (181 us = 751 TF). Ring-4 BK=32,
// depth-3 prefetch, counted vmcnt(8) at tile top (waits ONLY tile c's 4
// loads, issued 3 tiles earlier; c+1,c+2 stay in flight across the barrier —
// never drained to 0). R7-proven conflict-free packed layout (2 logical rows
// per 128-B LDS row; 0 conflicts measured R7/R8/R13/R14). Single read-burst
// + 32-MFMA cluster; compiler inserts counted lgkm waits.
// R15 change: s_setprio REMOVED — m190 A/B measured setprio negative on
// lockstep GEMM structures (this family). Everything else identical.
#define BM 256
#define BN 256
#define NKT 32  // K-tiles of 32

__global__ __launch_bounds__(512, 2) void k_score3(
    const unsigned short* __restrict__ Vb,   // values bf16 [M_TOT][H]
    const unsigned short* __restrict__ W1T,  // [UNITS][H] bf16
    const float* __restrict__ b1,
    const float* __restrict__ projq,         // [BATCH][UNITS]
    const float* __restrict__ V,
    float* __restrict__ scores)              // [M_TOT], pre-zeroed by k_prep
{
  __shared__ unsigned short As[4][128][64];  // 64 KB (ring of 4 K-tiles)
  __shared__ unsigned short Bs[4][128][64];  // 64 KB

  const int tid = threadIdx.x;
  const int lane = tid & 63;
  const int wave = tid >> 6;        // 0..7
  const int wm = wave >> 2;         // 0..1 -> rows wm*128..+128
  const int wn = wave & 3;          // 0..3 -> cols wn*64..+64
  const int li = lane & 15, hi = lane >> 4;
  const int lr2 = li >> 1;
  const int pcol = (((((li & 1) << 2) + hi) ^ lr2) & 7) << 3;  // read slot (halves)

  // XCD-bijective swizzle: all 4 N-tiles of an M-tile on one XCD, consecutive.
  const int g = blockIdx.x;
  const int xcd = g & 7;
  const int local = g >> 3;          // 0..127
  const int n_t = local & 3;
  const int m_t = xcd + ((local >> 2) << 3);  // 0..255, bijective
  const int m0 = m_t * BM;
  const int n0 = n_t * BN;

  // staging: chunk = 16 global rows x 32 halves = 1 KB = one gll16.
  // lane l: s=(l&7)^(l>>3); grow = 2*(l>>3)+(s>>2); gcol halves = (s&3)*8
  const int sL = (lane & 7) ^ (lane >> 3);
  const int srow = 2 * (lane >> 3) + (sL >> 2);
  const int scol = (sL & 3) << 3;

  auto STAGE_A = [&](int bf, int kt) {
#pragma unroll
    for (int q = 0; q < 2; ++q) {
      int mb = wave * 32 + q * 16;
      gll16(&Vb[(size_t)(m0 + mb + srow) * H + kt * 32 + scol],
            &As[bf][wave * 16 + q * 8][0]);
    }
  };
  auto STAGE_B = [&](int bf, int kt) {
#pragma unroll
    for (int q = 0; q < 2; ++q) {
      int mb = wave * 32 + q * 16;
      gll16(&W1T[(size_t)(n0 + mb + srow) * H + kt * 32 + scol],
            &Bs[bf][wave * 16 + q * 8][0]);
    }
  };

  f32x4 acc[8][4] = {};

  // prologue: stage tiles 0,1,2 (12 loads/wave; issue order = ledger order)
  STAGE_A(0, 0); STAGE_B(0, 0);
  STAGE_A(1, 1); STAGE_B(1, 1);
  STAGE_A(2, 2); STAGE_B(2, 2);

#pragma unroll 4
  for (int c = 0; c < NKT; ++c) {
    const int buf = c & 3;
    const int nbuf = (c + 3) & 3;
    const int cn = (c < NKT - 3) ? c + 3 : NKT - 1;  // tail: dup-stage tile 31

    // tile c's 4 loads landed (issued 3 tiles ago); c+1,c+2 stay in flight
    asm volatile("s_waitcnt vmcnt(8)" ::: "memory");
    __builtin_amdgcn_s_barrier();

    bf16x8 a[8], b[4];
#pragma unroll
    for (int i = 0; i < 8; ++i)
      a[i] = *reinterpret_cast<const bf16x8*>(&As[buf][wm * 64 + i * 8 + lr2][pcol]);
    STAGE_A(nbuf, cn);
#pragma unroll
    for (int j = 0; j < 4; ++j)
      b[j] = *reinterpret_cast<const bf16x8*>(&Bs[buf][wn * 32 + j * 8 + lr2][pcol]);
    STAGE_B(nbuf, cn);

#pragma unroll
    for (int i = 0; i < 8; ++i)
#pragma unroll
      for (int j = 0; j < 4; ++j)
        acc[i][j] = __builtin_amdgcn_mfma_f32_16x16x32_bf16(a[i], b[j], acc[i][j], 0, 0, 0);
  }

  // epilogue: partial score[row] = sum_u tanh(acc + b1[u] + projq[b][u]) * V[u]
  const int b = m0 >> 11;  // BM=256 divides SEQ=2048 -> batch uniform per block
  float bias[4], vv[4];
#pragma unroll
  for (int j = 0; j < 4; ++j) {
    int u = n0 + wn * 64 + j * 16 + li;
    bias[j] = b1[u] + projq[b * UNITS + u];
    vv[j] = V[u];
  }
#pragma unroll
  for (int mi = 0; mi < 8; ++mi) {
#pragma unroll
    for (int r = 0; r < 4; ++r) {
      float s = 0.f;
#pragma unroll
      for (int j = 0; j < 4; ++j) {
        float x = acc[mi][j][r] + bias[j];
        float e = __expf(2.f * x);       // tanh(x) = 1 - 2/(e^(2x)+1)
        s += (1.f - 2.f / (e + 1.f)) * vv[j];
      }
      s += __shfl_xor(s, 1);
      s += __shfl_xor(s, 2);
      s += __shfl_xor(s, 4);
      s += __shfl_xor(s, 8);
      if (li == 0) {
        int row = m0 + wm * 128 + mi * 16 + hi * 4 + r;
        atomicAdd(&scores[row], s);
      }
    }
  }
}

// ---- fallback kernels (used only if ws too small) ----
__global__ void k_transpose_w1(const float* __restrict__ W1, unsigned short* __restrict__ W1T) {
  __shared__ float tile[32][33];
  int bx = blockIdx.x, by = blockIdx.y;
  int tx = threadIdx.x, ty = threadIdx.y;
#pragma unroll
  for (int i = 0; i < 4; ++i)
    tile[ty + i * 8][tx] = W1[(by * 32 + ty + i * 8) * UNITS + bx * 32 + tx];
  __syncthreads();
#pragma unroll
  for (int i = 0; i < 4; ++i)
    W1T[(bx * 32 + ty + i * 8) * H + by * 32 + tx] = f2bf(tile[tx][ty + i * 8]);
}

__global__ void k_projq(const float* __restrict__ query, const float* __restrict__ W2,
                        const float* __restrict__ b2, float* __restrict__ projq) {
  __shared__ float q[H];
  int b = blockIdx.x;
  int u = blockIdx.y * 256 + threadIdx.x;
  for (int i = threadIdx.x; i < H; i += 256) q[i] = query[b * H + i];
  __syncthreads();
  float acc = 0.f;
#pragma unroll 8
  for (int k = 0; k < H; ++k) acc = fmaf(q[k], W2[k * UNITS + u], acc);
  projq[b * UNITS + u] = acc + b2[u];
}

#define FBM 128
#define FBN 128
#define FBK 64
#define LDK 72
__global__ __launch_bounds__(256) void k_score_f32(
    const float* __restrict__ values, const unsigned short* __restrict__ W1T,
    const float* __restrict__ b1, const float* __restrict__ projq,
    const float* __restrict__ V, float* __restrict__ scores)
{
  __shared__ unsigned short Asf[FBM][LDK];
  __shared__ unsigned short Bsf[FBN][LDK];
  const int tid = threadIdx.x;
  const int lane = tid & 63;
  const int wave = tid >> 6;
  const int wm = wave >> 1, wn = wave & 1;
  const int li = lane & 15, hi = lane >> 4;
  const int n0 = blockIdx.x * FBN;
  const int m0 = blockIdx.y * FBM;
  f32x4 acc[4][4] = {};
  for (int k0 = 0; k0 < H; k0 += FBK) {
    __syncthreads();
#pragma unroll
    for (int q = 0; q < 8; ++q) {
      int idx = q * 256 + tid;
      int row = idx >> 4;
      int kc = (idx & 15) << 2;
      float4 v = *reinterpret_cast<const float4*>(&values[(size_t)(m0 + row) * H + k0 + kc]);
      union { unsigned short h[4]; unsigned long long u64; } p;
      p.h[0] = f2bf(v.x); p.h[1] = f2bf(v.y); p.h[2] = f2bf(v.z); p.h[3] = f2bf(v.w);
      *reinterpret_cast<unsigned long long*>(&Asf[row][kc]) = p.u64;
    }
#pragma unroll
    for (int q = 0; q < 4; ++q) {
      int idx = q * 256 + tid;
      int row = idx >> 3;
      int kc = (idx & 7) << 3;
      *reinterpret_cast<u16x8*>(&Bsf[row][kc]) =
          *reinterpret_cast<const u16x8*>(&W1T[(size_t)(n0 + row) * H + k0 + kc]);
    }
    __syncthreads();
#pragma unroll
    for (int ks = 0; ks < 2; ++ks) {
      const int kofs = ks * 32 + 8 * hi;
      bf16x8 a[4], bb[4];
#pragma unroll
      for (int i = 0; i < 4; ++i)
        a[i] = *reinterpret_cast<const bf16x8*>(&Asf[wm * 64 + i * 16 + li][kofs]);
#pragma unroll
      for (int i = 0; i < 4; ++i)
        bb[i] = *reinterpret_cast<const bf16x8*>(&Bsf[wn * 64 + i * 16 + li][kofs]);
#pragma unroll
      for (int mi = 0; mi < 4; ++mi)
#pragma unroll
        for (int ni = 0; ni < 4; ++ni)
          acc[mi][ni] = __builtin_amdgcn_mfma_f32_16x16x32_bf16(a[mi], bb[ni], acc[mi][ni], 0, 0, 0);
    }
  }
  const int b = m0 >> 11;
  float bias[4], vv[4];
#pragma unroll
  for (int ni = 0; ni < 4; ++ni) {
    int u = n0 + wn * 64 + ni * 16 + li;
    bias[ni] = b1[u] + projq[b * UNITS + u];
    vv[ni] = V[u];
  }
#pragma unroll
  for (int mi = 0; mi < 4; ++mi) {
#pragma unroll
    for (int r = 0; r < 4; ++r) {
      float s = 0.f;
#pragma unroll
      for (int ni = 0; ni < 4; ++ni) {
        float x = acc[mi][ni][r] + bias[ni];
        float e = __expf(2.f * x);
        s += (1.f - 2.f / (e + 1.f)) * vv[ni];
      }
      s += __shfl_xor(s, 1);
      s += __shfl_xor(s, 2);
      s += __shfl_xor(s, 4);
      s += __shfl_xor(s, 8);
      if (li == 0) atomicAdd(&scores[m0 + wm * 64 + mi * 16 + hi * 4 + r], s);
    }
  }
}

// ---- softmax over S per batch; bv cancels ----
__global__ void k_softmax(const float* __restrict__ scores, float* __restrict__ wts) {
  __shared__ float red[8];
  int b = blockIdx.x;
  int t = threadIdx.x;
  float v[8];
  float mx = -3.4e38f;
#pragma unroll
  for (int i = 0; i < 8; ++i) {
    v[i] = scores[b * SEQ + i * 256 + t];
    mx = fmaxf(mx, v[i]);
  }
#pragma unroll
  for (int o = 1; o < 64; o <<= 1) mx = fmaxf(mx, __shfl_xor(mx, o));
  if ((t & 63) == 0) red[t >> 6] = mx;
  __syncthreads();
  mx = fmaxf(fmaxf(red[0], red[1]), fmaxf(red[2], red[3]));
  float sum = 0.f;
#pragma unroll
  for (int i = 0; i < 8; ++i) { v[i] = __expf(v[i] - mx); sum += v[i]; }
#pragma unroll
  for (int o = 1; o < 64; o <<= 1) sum += __shfl_xor(sum, o);
  if ((t & 63) == 0) red[4 + (t >> 6)] = sum;
  __syncthreads();
  float inv = 1.f / (red[4] + red[5] + red[6] + red[7]);
#pragma unroll
  for (int i = 0; i < 8; ++i) wts[b * SEQ + i * 256 + t] = v[i] * inv;
}

// ---- context from bf16 values: ctx[b][h] = sum_s w[b][s]*v[b][s][h] ----
// R15: 1024 blocks (64-s chunks) for more TLP on the latency/BW tail.
__global__ void k_context_bf(const unsigned short* __restrict__ Vb,
                             const float* __restrict__ wts, float* __restrict__ ctx) {
  int b = blockIdx.x, sc = blockIdx.y;
  int h4 = threadIdx.x * 4;
  const unsigned short* vb = Vb + (size_t)b * SEQ * H;
  float a0 = 0, a1 = 0, a2 = 0, a3 = 0;
  int s0 = sc * 64;
#pragma unroll 4
  for (int s = s0; s < s0 + 64; ++s) {
    float w = wts[b * SEQ + s];
    ushort4 v = *reinterpret_cast<const ushort4*>(&vb[(size_t)s * H + h4]);
    a0 = fmaf(w, bf2f(v.x), a0);
    a1 = fmaf(w, bf2f(v.y), a1);
    a2 = fmaf(w, bf2f(v.z), a2);
    a3 = fmaf(w, bf2f(v.w), a3);
  }
  atomicAdd(&ctx[b * H + h4 + 0], a0);
  atomicAdd(&ctx[b * H + h4 + 1], a1);
  atomicAdd(&ctx[b * H + h4 + 2], a2);
  atomicAdd(&ctx[b * H + h4 + 3], a3);
}

// ---- fp32 context (fallback path) ----
__global__ void k_context(const float* __restrict__ values, const float* __restrict__ wts,
                          float* __restrict__ ctx) {
  int b = blockIdx.x, hc = blockIdx.y, sc = blockIdx.z;
  int h = hc * 256 + threadIdx.x;
  const float* vb = values + (size_t)b * SEQ * H;
  float acc = 0.f;
  int s0 = sc * 128;
#pragma unroll 4
  for (int s = s0; s < s0 + 128; ++s)
    acc = fmaf(wts[b * SEQ + s], vb[(size_t)s * H + h], acc);
  atomicAdd(&ctx[b * H + h], acc);
}

extern "C" void kernel_launch(void* const* d_in, const int* in_sizes, int n_in,
                              void* d_out, int out_size, void* d_ws, size_t ws_size,
                              hipStream_t stream) {
  (void)in_sizes; (void)n_in; (void)out_size;
  const float* query  = (const float*)d_in[0];
  const float* values = (const float*)d_in[1];
  const float* W1     = (const float*)d_in[2];
  const float* b1     = (const float*)d_in[3];
  const float* W2     = (const float*)d_in[4];
  const float* b2     = (const float*)d_in[5];
  const float* V      = (const float*)d_in[6];
  // d_in[7] = bv: cancels in softmax -> unused.

  float* out = (float*)d_out;
  float* ctx = out;             // [32][1024]
  float* wts = out + BATCH * H; // [32][2048]

  const size_t vb_bytes = (size_t)M_TOT * H * 2;  // 128 MB
  const size_t need = vb_bytes + (2u << 20) + (256u << 10) + (128u << 10);

  if (ws_size >= need) {
    char* ws = (char*)d_ws;
    unsigned short* Vb  = (unsigned short*)ws;
    unsigned short* W1T = (unsigned short*)(ws + vb_bytes);
    float* scores = (float*)(ws + vb_bytes + (2u << 20));
    float* projq  = (float*)(ws + vb_bytes + (2u << 20) + (256u << 10));

    k_prep<<<3232, 256, 0, stream>>>(values, Vb, W1, W1T, query, W2, b2, projq,
                                     scores, ctx);
    k_score3<<<(M_TOT / BM) * (UNITS / BN), 512, 0, stream>>>(Vb, W1T, b1, projq, V, scores);
    k_softmax<<<BATCH, 256, 0, stream>>>(scores, wts);
    k_context_bf<<<dim3(BATCH, 32), 256, 0, stream>>>(Vb, wts, ctx);
  } else {
    char* ws = (char*)d_ws;
    unsigned short* W1T = (unsigned short*)ws;
    float* scores = (float*)(ws + (2u << 20));
    float* projq  = (float*)(ws + (2u << 20) + (256u << 10));

    hipMemsetAsync(scores, 0, M_TOT * sizeof(float), stream);
    hipMemsetAsync(ctx, 0, BATCH * H * sizeof(float), stream);

    k_transpose_w1<<<dim3(32, 32), dim3(32, 8), 0, stream>>>(W1, W1T);
    k_projq<<<dim3(32, 4), 256, 0, stream>>>(query, W2, b2, projq);
    k_score_f32<<<dim3(UNITS / FBN, M_TOT / FBM), 256, 0, stream>>>(values, W1T, b1, projq, V, scores);
    k_softmax<<<BATCH, 256, 0, stream>>>(scores, wts);
    k_context<<<dim3(BATCH, H / 256, 16), 256, 0, stream>>>(values, wts, ctx);
  }
}

// Round 17
// 316.918 us; speedup vs baseline: 1.0244x; 1.0244x over previous
//
#include <hip/hip_runtime.h>

#define H 1024
#define UNITS 1024
#define BATCH 32
#define SEQ 2048
#define M_TOT (BATCH * SEQ)  // 65536

typedef __attribute__((ext_vector_type(8))) short bf16x8;
typedef __attribute__((ext_vector_type(8))) unsigned short u16x8;
typedef __attribute__((ext_vector_type(4))) float f32x4;

__device__ __forceinline__ unsigned short f2bf(float f) {
  union { float f; unsigned u; } x; x.f = f;
  unsigned r = x.u + 0x7FFFu + ((x.u >> 16) & 1u);  // RTN-even
  return (unsigned short)(r >> 16);
}

// async global->LDS, 16B per lane; LDS dest = wave-uniform base + lane*16
__device__ __forceinline__ void gll16(const unsigned short* g, unsigned short* l) {
  __builtin_amdgcn_global_load_lds(
      (const __attribute__((address_space(1))) void*)g,
      (__attribute__((address_space(3))) void*)l, 16, 0, 0);
}

// ---- fused prep (no cast pass anymore): W1 transpose (0..1023) +
//      projq (1024..1151) + scores/ctx zero-fill (1152..1183).
__global__ void k_prep2(const float* __restrict__ W1, unsigned short* __restrict__ W1T,
                        const float* __restrict__ query, const float* __restrict__ W2,
                        const float* __restrict__ b2, float* __restrict__ projq,
                        float* __restrict__ scores, float* __restrict__ ctx) {
  __shared__ float sh[1056];  // aliased: tile[32][33] (4224B) / q[1024] (4096B)
  const int blk = blockIdx.x;
  const int tid = threadIdx.x;
  if (blk < 1024) {
    float (*tile)[33] = reinterpret_cast<float(*)[33]>(sh);
    const int bx = blk & 31, by = blk >> 5;
    const int tx = tid & 31, ty = tid >> 5;  // 32 x 8
#pragma unroll
    for (int i = 0; i < 4; ++i)
      tile[ty + i * 8][tx] = W1[(by * 32 + ty + i * 8) * UNITS + bx * 32 + tx];
    __syncthreads();
#pragma unroll
    for (int i = 0; i < 4; ++i)
      W1T[(bx * 32 + ty + i * 8) * H + by * 32 + tx] = f2bf(tile[tx][ty + i * 8]);
  } else if (blk < 1152) {
    float* q = sh;
    const int t = blk - 1024;       // 0..127
    const int b = t >> 2;
    const int u = (t & 3) * 256 + tid;
    for (int i = tid; i < H; i += 256) q[i] = query[b * H + i];
    __syncthreads();
    float acc = 0.f;
#pragma unroll 8
    for (int k = 0; k < H; ++k) acc = fmaf(q[k], W2[k * UNITS + u], acc);
    projq[b * UNITS + u] = acc + b2[u];
  } else {
    const int idx = (blk - 1152) * 256 + tid;  // 0..8191
    float4 z = make_float4(0.f, 0.f, 0.f, 0.f);
    *reinterpret_cast<float4*>(scores + idx * 8) = z;
    *reinterpret_cast<float4*>(scores + idx * 8 + 4) = z;
    *reinterpret_cast<float4*>(ctx + idx * 4) = z;
  }
}

// ============ 256x256 fused GEMM + tanh + dot(V), fp32-A direct ==============
// R8/R14's proven skeleton (ring B, counted vmcnt, packed conflict-free LDS,
// 0 conflicts) with the A-path reg-staged DIRECTLY FROM FP32 values —
// eliminating the 384 MB standalone cast pass (>=61 us of mandatory HBM).
//   A: per tile per lane: 4x float4 (2 rows x 8 f32) -> 16x f2bf (same RTN
//      as the old k_cast => bit-identical GEMM numerics) -> 2x ds_write_b128
//      to the EXACT bytes the old gll16 produced (same lane->slot mapping,
//      so the verified involution + read side are untouched). Write census:
//      8 lanes per bank-quad uniform = b128 floor (no conflicts).
//   Cross-tile cushion: A(c+2) loads issue at tile c, convert at tile c+1
//      (~3400 cyc >> 900 HBM latency). One fp32 reg set lives across MFMA
//      (+16 VGPR); sets alternate by compile-time naming (rule 20).
//   B: unchanged gll16 ring-4 (Bs[4][128][64], 64 KB). A: Abuf[2] (32 KB).
//   Ledger per tile: issue B(c+3) [2], then vmcnt(2) = drains A(c+1) regs +
//      B(c+2), leaves only B(c+3); "memory" clobber pins the A(c+2) loads
//      BELOW the wait so they are never force-drained. lgkmcnt(0) after the
//      MFMA cluster drains the A ds_writes before the tile-end barrier.
#define BM 256
#define BN 256
#define NKT 32  // K-tiles of 32

__global__ __launch_bounds__(512, 2) void k_score4(
    const float* __restrict__ values,        // fp32 [M_TOT][H]
    const unsigned short* __restrict__ W1T,  // [UNITS][H] bf16
    const float* __restrict__ b1,
    const float* __restrict__ projq,         // [BATCH][UNITS]
    const float* __restrict__ V,
    float* __restrict__ scores)              // [M_TOT], pre-zeroed by k_prep2
{
  __shared__ unsigned short As[2][128][64];  // 32 KB (A double buffer)
  __shared__ unsigned short Bs[4][128][64];  // 64 KB (B ring of 4)

  const int tid = threadIdx.x;
  const int lane = tid & 63;
  const int wave = tid >> 6;        // 0..7
  const int wm = wave >> 2;         // 0..1 -> rows wm*128..+128
  const int wn = wave & 3;          // 0..3 -> cols wn*64..+64
  const int li = lane & 15, hi = lane >> 4;
  const int lr2 = li >> 1;
  const int pcol = (((((li & 1) << 2) + hi) ^ lr2) & 7) << 3;  // read slot (halves)

  // XCD-bijective swizzle: all 4 N-tiles of an M-tile on one XCD, consecutive.
  const int g = blockIdx.x;
  const int xcd = g & 7;
  const int local = g >> 3;          // 0..127
  const int n_t = local & 3;
  const int m_t = xcd + ((local >> 2) << 3);  // 0..255, bijective
  const int m0 = m_t * BM;
  const int n0 = n_t * BN;

  // staging geometry (R7-proven involution): lane l: s=(l&7)^(l>>3);
  // srow=2*(l>>3)+(s>>2); scol=(s&3)*8
  const int sL = (lane & 7) ^ (lane >> 3);
  const int srow = 2 * (lane >> 3) + (sL >> 2);
  const int scol = (sL & 3) << 3;

  // A source base: chunk0 row for this lane; chunk1 = +16 rows
  const float* vA = values + (size_t)(m0 + wave * 32 + srow) * H + scol;
  const int arow = wave * 16 + (lane >> 3);       // LDS write row (chunk0; +8 chunk1)
  const int acol = (lane & 7) << 3;               // LDS write col (halves)

  auto STAGE_B = [&](int bf, int kt) {
#pragma unroll
    for (int q = 0; q < 2; ++q) {
      int mb = wave * 32 + q * 16;
      gll16(&W1T[(size_t)(n0 + mb + srow) * H + kt * 32 + scol],
            &Bs[bf][wave * 16 + q * 8][0]);
    }
  };
  auto LOAD_A = [&](int kt, float4* r) {
    const float* p0 = vA + kt * 32;
    const float* p1 = p0 + (size_t)16 * H;
    r[0] = *reinterpret_cast<const float4*>(p0);
    r[1] = *reinterpret_cast<const float4*>(p0 + 4);
    r[2] = *reinterpret_cast<const float4*>(p1);
    r[3] = *reinterpret_cast<const float4*>(p1 + 4);
  };
  auto CVTW = [&](int ab, const float4* r) {
    union { unsigned short h[8]; u16x8 v; } p0, p1;
    p0.h[0] = f2bf(r[0].x); p0.h[1] = f2bf(r[0].y);
    p0.h[2] = f2bf(r[0].z); p0.h[3] = f2bf(r[0].w);
    p0.h[4] = f2bf(r[1].x); p0.h[5] = f2bf(r[1].y);
    p0.h[6] = f2bf(r[1].z); p0.h[7] = f2bf(r[1].w);
    p1.h[0] = f2bf(r[2].x); p1.h[1] = f2bf(r[2].y);
    p1.h[2] = f2bf(r[2].z); p1.h[3] = f2bf(r[2].w);
    p1.h[4] = f2bf(r[3].x); p1.h[5] = f2bf(r[3].y);
    p1.h[6] = f2bf(r[3].z); p1.h[7] = f2bf(r[3].w);
    *reinterpret_cast<u16x8*>(&As[ab][arow][acol]) = p0.v;
    *reinterpret_cast<u16x8*>(&As[ab][arow + 8][acol]) = p1.v;
  };

  f32x4 acc[8][4] = {};
  float4 fA[4], fB[4];  // two named fp32 staging sets (rule 20)

  // ---- prologue ----
  LOAD_A(0, fA);                         // A0 regs (4 vm)
  STAGE_B(0, 0); STAGE_B(1, 1); STAGE_B(2, 2);  // B0,B1,B2 (6 vm)
  asm volatile("s_waitcnt vmcnt(6)" ::: "memory");   // A0 landed
  CVTW(0, fA);                           // A0 -> Abuf0
  LOAD_A(1, fB);                         // A1 regs (4 vm)
  asm volatile("s_waitcnt vmcnt(8)" ::: "memory");   // B0 landed (B1,B2,A1 fly)
  asm volatile("s_waitcnt lgkmcnt(0)" ::: "memory"); // A0 writes done
  __builtin_amdgcn_s_barrier();

  // tile body: frag reads -> issue B(c+3) -> vmcnt(2) -> cvt A(c+1) ->
  //            load A(c+2) -> 32 MFMA -> lgkm(0) -> barrier
  auto TILE = [&](int c, float4* fCvt, float4* fLoad) {
    bf16x8 a[8], b[4];
#pragma unroll
    for (int i = 0; i < 8; ++i)
      a[i] = *reinterpret_cast<const bf16x8*>(&As[c & 1][wm * 64 + i * 8 + lr2][pcol]);
#pragma unroll
    for (int j = 0; j < 4; ++j)
      b[j] = *reinterpret_cast<const bf16x8*>(&Bs[c & 3][wn * 32 + j * 8 + lr2][pcol]);
    STAGE_B((c + 3) & 3, (c + 3 < NKT) ? c + 3 : NKT - 1);
    // drains A(c+1) regs + B(c+2); leaves only the just-issued B(c+3)
    asm volatile("s_waitcnt vmcnt(2)" ::: "memory");
    CVTW((c + 1) & 1, fCvt);             // A(c+1) -> LDS (read next tile)
    LOAD_A((c + 2 < NKT) ? c + 2 : NKT - 1, fLoad);  // A(c+2) regs (4 vm)
#pragma unroll
    for (int i = 0; i < 8; ++i)
#pragma unroll
      for (int j = 0; j < 4; ++j)
        acc[i][j] = __builtin_amdgcn_mfma_f32_16x16x32_bf16(a[i], b[j], acc[i][j], 0, 0, 0);
    asm volatile("s_waitcnt lgkmcnt(0)" ::: "memory");  // A writes drained
    __builtin_amdgcn_s_barrier();
  };

#pragma unroll 2
  for (int c = 0; c < NKT; c += 2) {
    TILE(c, fB, fA);      // computes c; cvt A(c+1) from fB; load A(c+2)->fA
    TILE(c + 1, fA, fB);  // computes c+1; cvt A(c+2) from fA; load A(c+3)->fB
  }

  // epilogue: partial score[row] = sum_u tanh(acc + b1[u] + projq[b][u]) * V[u]
  const int b = m0 >> 11;  // BM=256 divides SEQ=2048 -> batch uniform per block
  float bias[4], vv[4];
#pragma unroll
  for (int j = 0; j < 4; ++j) {
    int u = n0 + wn * 64 + j * 16 + li;
    bias[j] = b1[u] + projq[b * UNITS + u];
    vv[j] = V[u];
  }
#pragma unroll
  for (int mi = 0; mi < 8; ++mi) {
#pragma unroll
    for (int r = 0; r < 4; ++r) {
      float s = 0.f;
#pragma unroll
      for (int j = 0; j < 4; ++j) {
        float x = acc[mi][j][r] + bias[j];
        float e = __expf(2.f * x);       // tanh(x) = 1 - 2/(e^(2x)+1)
        s += (1.f - 2.f / (e + 1.f)) * vv[j];
      }
      s += __shfl_xor(s, 1);
      s += __shfl_xor(s, 2);
      s += __shfl_xor(s, 4);
      s += __shfl_xor(s, 8);
      if (li == 0) {
        int row = m0 + wm * 128 + mi * 16 + hi * 4 + r;
        atomicAdd(&scores[row], s);
      }
    }
  }
}

// ---- fallback kernels (used only if ws too small) ----
__global__ void k_transpose_w1(const float* __restrict__ W1, unsigned short* __restrict__ W1T) {
  __shared__ float tile[32][33];
  int bx = blockIdx.x, by = blockIdx.y;
  int tx = threadIdx.x, ty = threadIdx.y;
#pragma unroll
  for (int i = 0; i < 4; ++i)
    tile[ty + i * 8][tx] = W1[(by * 32 + ty + i * 8) * UNITS + bx * 32 + tx];
  __syncthreads();
#pragma unroll
  for (int i = 0; i < 4; ++i)
    W1T[(bx * 32 + ty + i * 8) * H + by * 32 + tx] = f2bf(tile[tx][ty + i * 8]);
}

__global__ void k_projq(const float* __restrict__ query, const float* __restrict__ W2,
                        const float* __restrict__ b2, float* __restrict__ projq) {
  __shared__ float q[H];
  int b = blockIdx.x;
  int u = blockIdx.y * 256 + threadIdx.x;
  for (int i = threadIdx.x; i < H; i += 256) q[i] = query[b * H + i];
  __syncthreads();
  float acc = 0.f;
#pragma unroll 8
  for (int k = 0; k < H; ++k) acc = fmaf(q[k], W2[k * UNITS + u], acc);
  projq[b * UNITS + u] = acc + b2[u];
}

#define FBM 128
#define FBN 128
#define FBK 64
#define LDK 72
__global__ __launch_bounds__(256) void k_score_f32(
    const float* __restrict__ values, const unsigned short* __restrict__ W1T,
    const float* __restrict__ b1, const float* __restrict__ projq,
    const float* __restrict__ V, float* __restrict__ scores)
{
  __shared__ unsigned short Asf[FBM][LDK];
  __shared__ unsigned short Bsf[FBN][LDK];
  const int tid = threadIdx.x;
  const int lane = tid & 63;
  const int wave = tid >> 6;
  const int wm = wave >> 1, wn = wave & 1;
  const int li = lane & 15, hi = lane >> 4;
  const int n0 = blockIdx.x * FBN;
  const int m0 = blockIdx.y * FBM;
  f32x4 acc[4][4] = {};
  for (int k0 = 0; k0 < H; k0 += FBK) {
    __syncthreads();
#pragma unroll
    for (int q = 0; q < 8; ++q) {
      int idx = q * 256 + tid;
      int row = idx >> 4;
      int kc = (idx & 15) << 2;
      float4 v = *reinterpret_cast<const float4*>(&values[(size_t)(m0 + row) * H + k0 + kc]);
      union { unsigned short h[4]; unsigned long long u64; } p;
      p.h[0] = f2bf(v.x); p.h[1] = f2bf(v.y); p.h[2] = f2bf(v.z); p.h[3] = f2bf(v.w);
      *reinterpret_cast<unsigned long long*>(&Asf[row][kc]) = p.u64;
    }
#pragma unroll
    for (int q = 0; q < 4; ++q) {
      int idx = q * 256 + tid;
      int row = idx >> 3;
      int kc = (idx & 7) << 3;
      *reinterpret_cast<u16x8*>(&Bsf[row][kc]) =
          *reinterpret_cast<const u16x8*>(&W1T[(size_t)(n0 + row) * H + k0 + kc]);
    }
    __syncthreads();
#pragma unroll
    for (int ks = 0; ks < 2; ++ks) {
      const int kofs = ks * 32 + 8 * hi;
      bf16x8 a[4], bb[4];
#pragma unroll
      for (int i = 0; i < 4; ++i)
        a[i] = *reinterpret_cast<const bf16x8*>(&Asf[wm * 64 + i * 16 + li][kofs]);
#pragma unroll
      for (int i = 0; i < 4; ++i)
        bb[i] = *reinterpret_cast<const bf16x8*>(&Bsf[wn * 64 + i * 16 + li][kofs]);
#pragma unroll
      for (int mi = 0; mi < 4; ++mi)
#pragma unroll
        for (int ni = 0; ni < 4; ++ni)
          acc[mi][ni] = __builtin_amdgcn_mfma_f32_16x16x32_bf16(a[mi], bb[ni], acc[mi][ni], 0, 0, 0);
    }
  }
  const int b = m0 >> 11;
  float bias[4], vv[4];
#pragma unroll
  for (int ni = 0; ni < 4; ++ni) {
    int u = n0 + wn * 64 + ni * 16 + li;
    bias[ni] = b1[u] + projq[b * UNITS + u];
    vv[ni] = V[u];
  }
#pragma unroll
  for (int mi = 0; mi < 4; ++mi) {
#pragma unroll
    for (int r = 0; r < 4; ++r) {
      float s = 0.f;
#pragma unroll
      for (int ni = 0; ni < 4; ++ni) {
        float x = acc[mi][ni][r] + bias[ni];
        float e = __expf(2.f * x);
        s += (1.f - 2.f / (e + 1.f)) * vv[ni];
      }
      s += __shfl_xor(s, 1);
      s += __shfl_xor(s, 2);
      s += __shfl_xor(s, 4);
      s += __shfl_xor(s, 8);
      if (li == 0) atomicAdd(&scores[m0 + wm * 64 + mi * 16 + hi * 4 + r], s);
    }
  }
}

// ---- softmax over S per batch; bv cancels ----
__global__ void k_softmax(const float* __restrict__ scores, float* __restrict__ wts) {
  __shared__ float red[8];
  int b = blockIdx.x;
  int t = threadIdx.x;
  float v[8];
  float mx = -3.4e38f;
#pragma unroll
  for (int i = 0; i < 8; ++i) {
    v[i] = scores[b * SEQ + i * 256 + t];
    mx = fmaxf(mx, v[i]);
  }
#pragma unroll
  for (int o = 1; o < 64; o <<= 1) mx = fmaxf(mx, __shfl_xor(mx, o));
  if ((t & 63) == 0) red[t >> 6] = mx;
  __syncthreads();
  mx = fmaxf(fmaxf(red[0], red[1]), fmaxf(red[2], red[3]));
  float sum = 0.f;
#pragma unroll
  for (int i = 0; i < 8; ++i) { v[i] = __expf(v[i] - mx); sum += v[i]; }
#pragma unroll
  for (int o = 1; o < 64; o <<= 1) sum += __shfl_xor(sum, o);
  if ((t & 63) == 0) red[4 + (t >> 6)] = sum;
  __syncthreads();
  float inv = 1.f / (red[4] + red[5] + red[6] + red[7]);
#pragma unroll
  for (int i = 0; i < 8; ++i) wts[b * SEQ + i * 256 + t] = v[i] * inv;
}

// ---- context from fp32 values (vectorized): ctx[b][h]=sum_s w*v ----
__global__ void k_context_f32v(const float* __restrict__ values,
                               const float* __restrict__ wts, float* __restrict__ ctx) {
  int b = blockIdx.x, sc = blockIdx.y;
  int h4 = threadIdx.x * 4;
  const float* vb = values + (size_t)b * SEQ * H;
  float a0 = 0, a1 = 0, a2 = 0, a3 = 0;
  int s0 = sc * 64;
#pragma unroll 4
  for (int s = s0; s < s0 + 64; ++s) {
    float w = wts[b * SEQ + s];
    float4 v = *reinterpret_cast<const float4*>(&vb[(size_t)s * H + h4]);
    a0 = fmaf(w, v.x, a0);
    a1 = fmaf(w, v.y, a1);
    a2 = fmaf(w, v.z, a2);
    a3 = fmaf(w, v.w, a3);
  }
  atomicAdd(&ctx[b * H + h4 + 0], a0);
  atomicAdd(&ctx[b * H + h4 + 1], a1);
  atomicAdd(&ctx[b * H + h4 + 2], a2);
  atomicAdd(&ctx[b * H + h4 + 3], a3);
}

// ---- fp32 context (fallback path) ----
__global__ void k_context(const float* __restrict__ values, const float* __restrict__ wts,
                          float* __restrict__ ctx) {
  int b = blockIdx.x, hc = blockIdx.y, sc = blockIdx.z;
  int h = hc * 256 + threadIdx.x;
  const float* vb = values + (size_t)b * SEQ * H;
  float acc = 0.f;
  int s0 = sc * 128;
#pragma unroll 4
  for (int s = s0; s < s0 + 128; ++s)
    acc = fmaf(wts[b * SEQ + s], vb[(size_t)s * H + h], acc);
  atomicAdd(&ctx[b * H + h], acc);
}

extern "C" void kernel_launch(void* const* d_in, const int* in_sizes, int n_in,
                              void* d_out, int out_size, void* d_ws, size_t ws_size,
                              hipStream_t stream) {
  (void)in_sizes; (void)n_in; (void)out_size;
  const float* query  = (const float*)d_in[0];
  const float* values = (const float*)d_in[1];
  const float* W1     = (const float*)d_in[2];
  const float* b1     = (const float*)d_in[3];
  const float* W2     = (const float*)d_in[4];
  const float* b2     = (const float*)d_in[5];
  const float* V      = (const float*)d_in[6];
  // d_in[7] = bv: cancels in softmax -> unused.

  float* out = (float*)d_out;
  float* ctx = out;             // [32][1024]
  float* wts = out + BATCH * H; // [32][2048]

  const size_t need = (2u << 20) + (256u << 10) + (128u << 10);  // W1T+scores+projq

  if (ws_size >= need) {
    char* ws = (char*)d_ws;
    unsigned short* W1T = (unsigned short*)ws;                   // 2 MB
    float* scores = (float*)(ws + (2u << 20));                   // 256 KB
    float* projq  = (float*)(ws + (2u << 20) + (256u << 10));    // 128 KB

    k_prep2<<<1184, 256, 0, stream>>>(W1, W1T, query, W2, b2, projq, scores, ctx);
    k_score4<<<(M_TOT / BM) * (UNITS / BN), 512, 0, stream>>>(values, W1T, b1, projq, V, scores);
    k_softmax<<<BATCH, 256, 0, stream>>>(scores, wts);
    k_context_f32v<<<dim3(BATCH, 32), 256, 0, stream>>>(values, wts, ctx);
  } else {
    char* ws = (char*)d_ws;
    unsigned short* W1T = (unsigned short*)ws;
    float* scores = (float*)(ws + (2u << 20));
    float* projq  = (float*)(ws + (2u << 20) + (256u << 10));

    hipMemsetAsync(scores, 0, M_TOT * sizeof(float), stream);
    hipMemsetAsync(ctx, 0, BATCH * H * sizeof(float), stream);

    k_transpose_w1<<<dim3(32, 32), dim3(32, 8), 0, stream>>>(W1, W1T);
    k_projq<<<dim3(32, 4), 256, 0, stream>>>(query, W2, b2, projq);
    k_score_f32<<<dim3(UNITS / FBN, M_TOT / FBM), 256, 0, stream>>>(values, W1T, b1, projq, V, scores);
    k_softmax<<<BATCH, 256, 0, stream>>>(scores, wts);
    k_context<<<dim3(BATCH, H / 256, 16), 256, 0, stream>>>(values, wts, ctx);
  }
}

// Round 18
// 297.972 us; speedup vs baseline: 1.0896x; 1.0636x over previous
//
#include <hip/hip_runtime.h>

#define H 1024
#define UNITS 1024
#define BATCH 32
#define SEQ 2048
#define M_TOT (BATCH * SEQ)  // 65536

typedef __attribute__((ext_vector_type(8))) short bf16x8;
typedef __attribute__((ext_vector_type(8))) unsigned short u16x8;
typedef __attribute__((ext_vector_type(4))) float f32x4;

__device__ __forceinline__ unsigned short f2bf(float f) {
  union { float f; unsigned u; } x; x.f = f;
  unsigned r = x.u + 0x7FFFu + ((x.u >> 16) & 1u);  // RTN-even
  return (unsigned short)(r >> 16);
}

// async global->LDS, 16B per lane; LDS dest = wave-uniform base + lane*16
__device__ __forceinline__ void gll16(const unsigned short* g, unsigned short* l) {
  __builtin_amdgcn_global_load_lds(
      (const __attribute__((address_space(1))) void*)g,
      (__attribute__((address_space(3))) void*)l, 16, 0, 0);
}

// ---- fused prep: W1 transpose (0..1023) + projq (1024..1151) +
//      scores/ctx zero-fill (1152..1183).
__global__ void k_prep2(const float* __restrict__ W1, unsigned short* __restrict__ W1T,
                        const float* __restrict__ query, const float* __restrict__ W2,
                        const float* __restrict__ b2, float* __restrict__ projq,
                        float* __restrict__ scores, float* __restrict__ ctx) {
  __shared__ float sh[1056];  // aliased: tile[32][33] (4224B) / q[1024] (4096B)
  const int blk = blockIdx.x;
  const int tid = threadIdx.x;
  if (blk < 1024) {
    float (*tile)[33] = reinterpret_cast<float(*)[33]>(sh);
    const int bx = blk & 31, by = blk >> 5;
    const int tx = tid & 31, ty = tid >> 5;  // 32 x 8
#pragma unroll
    for (int i = 0; i < 4; ++i)
      tile[ty + i * 8][tx] = W1[(by * 32 + ty + i * 8) * UNITS + bx * 32 + tx];
    __syncthreads();
#pragma unroll
    for (int i = 0; i < 4; ++i)
      W1T[(bx * 32 + ty + i * 8) * H + by * 32 + tx] = f2bf(tile[tx][ty + i * 8]);
  } else if (blk < 1152) {
    float* q = sh;
    const int t = blk - 1024;       // 0..127
    const int b = t >> 2;
    const int u = (t & 3) * 256 + tid;
    for (int i = tid; i < H; i += 256) q[i] = query[b * H + i];
    __syncthreads();
    float acc = 0.f;
#pragma unroll 8
    for (int k = 0; k < H; ++k) acc = fmaf(q[k], W2[k * UNITS + u], acc);
    projq[b * UNITS + u] = acc + b2[u];
  } else {
    const int idx = (blk - 1152) * 256 + tid;  // 0..8191
    float4 z = make_float4(0.f, 0.f, 0.f, 0.f);
    *reinterpret_cast<float4*>(scores + idx * 8) = z;
    *reinterpret_cast<float4*>(scores + idx * 8 + 4) = z;
    *reinterpret_cast<float4*>(ctx + idx * 4) = z;
  }
}

// ============ 256x256 fused GEMM + tanh + dot(V), fp32-A direct ==============
// R16 architecture (no standalone cast pass) with the A-path ledger FIXED:
// R16's vmcnt(2) gave A only a 1-tile cushion AND force-drained B(c+2),
// destroying R8's 3-tile B cushion (k_score4 regressed 181->279, MfmaUtil
// 20.7%). Now BOTH streams are depth-3 with a group-drain ledger:
//   per tile c issue: STAGE_B(c+3) [2 vm] + LOAD_A(c+3)->regset (c+3)&3 [4 vm]
//   at tile c: vmcnt(12) drains EXACTLY tile c-2's group {B(c+1), A(c+1)} —
//   both 2-tile (~10k cyc) cushion; robust to intra-tile issue reordering
//   (groups are ordered in the queue even if B/A interleave within a tile).
//   B(c) for this tile's frag reads was drained at tile c-1, before the
//   barrier. CVT A(c+1) right after the wait (regs also compiler-auto-waited).
// 4 named fp32 reg sets rotate compile-time under unroll-4 (rule 20):
//   c%4==0: cvt f1, load f3 | 1: cvt f2, load f0 | 2: cvt f3, load f1
//   | 3: cvt f0, load f2.
// CVTW writes the EXACT packed bytes of the proven involution (0 conflicts).
#define BM 256
#define BN 256
#define NKT 32  // K-tiles of 32

__global__ __launch_bounds__(512, 2) void k_score4(
    const float* __restrict__ values,        // fp32 [M_TOT][H]
    const unsigned short* __restrict__ W1T,  // [UNITS][H] bf16
    const float* __restrict__ b1,
    const float* __restrict__ projq,         // [BATCH][UNITS]
    const float* __restrict__ V,
    float* __restrict__ scores)              // [M_TOT], pre-zeroed by k_prep2
{
  __shared__ unsigned short As[2][128][64];  // 32 KB (A double buffer)
  __shared__ unsigned short Bs[4][128][64];  // 64 KB (B ring of 4)

  const int tid = threadIdx.x;
  const int lane = tid & 63;
  const int wave = tid >> 6;        // 0..7
  const int wm = wave >> 2;         // 0..1 -> rows wm*128..+128
  const int wn = wave & 3;          // 0..3 -> cols wn*64..+64
  const int li = lane & 15, hi = lane >> 4;
  const int lr2 = li >> 1;
  const int pcol = (((((li & 1) << 2) + hi) ^ lr2) & 7) << 3;  // read slot (halves)

  // XCD-bijective swizzle: all 4 N-tiles of an M-tile on one XCD, consecutive.
  const int g = blockIdx.x;
  const int xcd = g & 7;
  const int local = g >> 3;          // 0..127
  const int n_t = local & 3;
  const int m_t = xcd + ((local >> 2) << 3);  // 0..255, bijective
  const int m0 = m_t * BM;
  const int n0 = n_t * BN;

  // staging geometry (proven involution): lane l: s=(l&7)^(l>>3);
  // srow=2*(l>>3)+(s>>2); scol=(s&3)*8
  const int sL = (lane & 7) ^ (lane >> 3);
  const int srow = 2 * (lane >> 3) + (sL >> 2);
  const int scol = (sL & 3) << 3;

  // A source base: chunk0 row for this lane; chunk1 = +16 rows
  const float* vA = values + (size_t)(m0 + wave * 32 + srow) * H + scol;
  const int arow = wave * 16 + (lane >> 3);       // LDS write row (chunk0; +8 chunk1)
  const int acol = (lane & 7) << 3;               // LDS write col (halves)

  auto STAGE_B = [&](int bf, int kt) {
#pragma unroll
    for (int q = 0; q < 2; ++q) {
      int mb = wave * 32 + q * 16;
      gll16(&W1T[(size_t)(n0 + mb + srow) * H + kt * 32 + scol],
            &Bs[bf][wave * 16 + q * 8][0]);
    }
  };
  auto LOAD_A = [&](int kt, float4* r) {
    const float* p0 = vA + kt * 32;
    const float* p1 = p0 + (size_t)16 * H;
    r[0] = *reinterpret_cast<const float4*>(p0);
    r[1] = *reinterpret_cast<const float4*>(p0 + 4);
    r[2] = *reinterpret_cast<const float4*>(p1);
    r[3] = *reinterpret_cast<const float4*>(p1 + 4);
  };
  auto CVTW = [&](int ab, const float4* r) {
    union { unsigned short h[8]; u16x8 v; } p0, p1;
    p0.h[0] = f2bf(r[0].x); p0.h[1] = f2bf(r[0].y);
    p0.h[2] = f2bf(r[0].z); p0.h[3] = f2bf(r[0].w);
    p0.h[4] = f2bf(r[1].x); p0.h[5] = f2bf(r[1].y);
    p0.h[6] = f2bf(r[1].z); p0.h[7] = f2bf(r[1].w);
    p1.h[0] = f2bf(r[2].x); p1.h[1] = f2bf(r[2].y);
    p1.h[2] = f2bf(r[2].z); p1.h[3] = f2bf(r[2].w);
    p1.h[4] = f2bf(r[3].x); p1.h[5] = f2bf(r[3].y);
    p1.h[6] = f2bf(r[3].z); p1.h[7] = f2bf(r[3].w);
    *reinterpret_cast<u16x8*>(&As[ab][arow][acol]) = p0.v;
    *reinterpret_cast<u16x8*>(&As[ab][arow + 8][acol]) = p1.v;
  };

  f32x4 acc[8][4] = {};
  float4 f0[4], f1[4], f2[4], f3[4];  // 4 named fp32 staging sets (rule 20)

  // ---- prologue ----
  LOAD_A(0, f0);                                 // A0 (4 vm)
  LOAD_A(1, f1);                                 // A1 (4 vm)
  STAGE_B(0, 0); STAGE_B(1, 1); STAGE_B(2, 2);   // B0,B1,B2 (6 vm) -> 14
  asm volatile("s_waitcnt vmcnt(4)" ::: "memory");  // conservatively drains A0,A1,B0(+)
  CVTW(0, f0);                                   // A0 -> As[0]
  LOAD_A(2, f2);                                 // A2 (4 vm)
  asm volatile("s_waitcnt lgkmcnt(0)" ::: "memory");  // A0 writes done
  __builtin_amdgcn_s_barrier();

  // tile body: frag reads -> issue B(c+3)+A(c+3) -> vmcnt(12) [drains tile
  // c-2's group: B(c+1)+A(c+1), 2-tile cushion] -> cvt A(c+1) -> MFMA ->
  // lgkm(0) -> barrier.
  auto TILE = [&](int c, float4* fCvt, float4* fLoad) {
    bf16x8 a[8], b[4];
#pragma unroll
    for (int i = 0; i < 8; ++i)
      a[i] = *reinterpret_cast<const bf16x8*>(&As[c & 1][wm * 64 + i * 8 + lr2][pcol]);
#pragma unroll
    for (int j = 0; j < 4; ++j)
      b[j] = *reinterpret_cast<const bf16x8*>(&Bs[c & 3][wn * 32 + j * 8 + lr2][pcol]);
    const int cn = (c + 3 < NKT) ? c + 3 : NKT - 1;  // tail: dup loads (ledger)
    STAGE_B((c + 3) & 3, cn);
    LOAD_A(cn, fLoad);
    asm volatile("s_waitcnt vmcnt(12)" ::: "memory");
    CVTW((c + 1) & 1, fCvt);             // A(c+1) -> LDS (read next tile)
#pragma unroll
    for (int i = 0; i < 8; ++i)
#pragma unroll
      for (int j = 0; j < 4; ++j)
        acc[i][j] = __builtin_amdgcn_mfma_f32_16x16x32_bf16(a[i], b[j], acc[i][j], 0, 0, 0);
    asm volatile("s_waitcnt lgkmcnt(0)" ::: "memory");  // A writes drained
    __builtin_amdgcn_s_barrier();
  };

#pragma unroll 1
  for (int c = 0; c < NKT; c += 4) {
    TILE(c + 0, f1, f3);  // cvt A(c+1) from f1; load A(c+3) -> f3
    TILE(c + 1, f2, f0);
    TILE(c + 2, f3, f1);
    TILE(c + 3, f0, f2);
  }

  asm volatile("s_waitcnt vmcnt(0)" ::: "memory");  // drain dangling dup loads
  __builtin_amdgcn_s_barrier();

  // epilogue: partial score[row] = sum_u tanh(acc + b1[u] + projq[b][u]) * V[u]
  const int b = m0 >> 11;  // BM=256 divides SEQ=2048 -> batch uniform per block
  float bias[4], vv[4];
#pragma unroll
  for (int j = 0; j < 4; ++j) {
    int u = n0 + wn * 64 + j * 16 + li;
    bias[j] = b1[u] + projq[b * UNITS + u];
    vv[j] = V[u];
  }
#pragma unroll
  for (int mi = 0; mi < 8; ++mi) {
#pragma unroll
    for (int r = 0; r < 4; ++r) {
      float s = 0.f;
#pragma unroll
      for (int j = 0; j < 4; ++j) {
        float x = acc[mi][j][r] + bias[j];
        float e = __expf(2.f * x);       // tanh(x) = 1 - 2/(e^(2x)+1)
        s += (1.f - 2.f / (e + 1.f)) * vv[j];
      }
      s += __shfl_xor(s, 1);
      s += __shfl_xor(s, 2);
      s += __shfl_xor(s, 4);
      s += __shfl_xor(s, 8);
      if (li == 0) {
        int row = m0 + wm * 128 + mi * 16 + hi * 4 + r;
        atomicAdd(&scores[row], s);
      }
    }
  }
}

// ---- fallback kernels (used only if ws too small) ----
__global__ void k_transpose_w1(const float* __restrict__ W1, unsigned short* __restrict__ W1T) {
  __shared__ float tile[32][33];
  int bx = blockIdx.x, by = blockIdx.y;
  int tx = threadIdx.x, ty = threadIdx.y;
#pragma unroll
  for (int i = 0; i < 4; ++i)
    tile[ty + i * 8][tx] = W1[(by * 32 + ty + i * 8) * UNITS + bx * 32 + tx];
  __syncthreads();
#pragma unroll
  for (int i = 0; i < 4; ++i)
    W1T[(bx * 32 + ty + i * 8) * H + by * 32 + tx] = f2bf(tile[tx][ty + i * 8]);
}

__global__ void k_projq(const float* __restrict__ query, const float* __restrict__ W2,
                        const float* __restrict__ b2, float* __restrict__ projq) {
  __shared__ float q[H];
  int b = blockIdx.x;
  int u = blockIdx.y * 256 + threadIdx.x;
  for (int i = threadIdx.x; i < H; i += 256) q[i] = query[b * H + i];
  __syncthreads();
  float acc = 0.f;
#pragma unroll 8
  for (int k = 0; k < H; ++k) acc = fmaf(q[k], W2[k * UNITS + u], acc);
  projq[b * UNITS + u] = acc + b2[u];
}

#define FBM 128
#define FBN 128
#define FBK 64
#define LDK 72
__global__ __launch_bounds__(256) void k_score_f32(
    const float* __restrict__ values, const unsigned short* __restrict__ W1T,
    const float* __restrict__ b1, const float* __restrict__ projq,
    const float* __restrict__ V, float* __restrict__ scores)
{
  __shared__ unsigned short Asf[FBM][LDK];
  __shared__ unsigned short Bsf[FBN][LDK];
  const int tid = threadIdx.x;
  const int lane = tid & 63;
  const int wave = tid >> 6;
  const int wm = wave >> 1, wn = wave & 1;
  const int li = lane & 15, hi = lane >> 4;
  const int n0 = blockIdx.x * FBN;
  const int m0 = blockIdx.y * FBM;
  f32x4 acc[4][4] = {};
  for (int k0 = 0; k0 < H; k0 += FBK) {
    __syncthreads();
#pragma unroll
    for (int q = 0; q < 8; ++q) {
      int idx = q * 256 + tid;
      int row = idx >> 4;
      int kc = (idx & 15) << 2;
      float4 v = *reinterpret_cast<const float4*>(&values[(size_t)(m0 + row) * H + k0 + kc]);
      union { unsigned short h[4]; unsigned long long u64; } p;
      p.h[0] = f2bf(v.x); p.h[1] = f2bf(v.y); p.h[2] = f2bf(v.z); p.h[3] = f2bf(v.w);
      *reinterpret_cast<unsigned long long*>(&Asf[row][kc]) = p.u64;
    }
#pragma unroll
    for (int q = 0; q < 4; ++q) {
      int idx = q * 256 + tid;
      int row = idx >> 3;
      int kc = (idx & 7) << 3;
      *reinterpret_cast<u16x8*>(&Bsf[row][kc]) =
          *reinterpret_cast<const u16x8*>(&W1T[(size_t)(n0 + row) * H + k0 + kc]);
    }
    __syncthreads();
#pragma unroll
    for (int ks = 0; ks < 2; ++ks) {
      const int kofs = ks * 32 + 8 * hi;
      bf16x8 a[4], bb[4];
#pragma unroll
      for (int i = 0; i < 4; ++i)
        a[i] = *reinterpret_cast<const bf16x8*>(&Asf[wm * 64 + i * 16 + li][kofs]);
#pragma unroll
      for (int i = 0; i < 4; ++i)
        bb[i] = *reinterpret_cast<const bf16x8*>(&Bsf[wn * 64 + i * 16 + li][kofs]);
#pragma unroll
      for (int mi = 0; mi < 4; ++mi)
#pragma unroll
        for (int ni = 0; ni < 4; ++ni)
          acc[mi][ni] = __builtin_amdgcn_mfma_f32_16x16x32_bf16(a[mi], bb[ni], acc[mi][ni], 0, 0, 0);
    }
  }
  const int b = m0 >> 11;
  float bias[4], vv[4];
#pragma unroll
  for (int ni = 0; ni < 4; ++ni) {
    int u = n0 + wn * 64 + ni * 16 + li;
    bias[ni] = b1[u] + projq[b * UNITS + u];
    vv[ni] = V[u];
  }
#pragma unroll
  for (int mi = 0; mi < 4; ++mi) {
#pragma unroll
    for (int r = 0; r < 4; ++r) {
      float s = 0.f;
#pragma unroll
      for (int ni = 0; ni < 4; ++ni) {
        float x = acc[mi][ni][r] + bias[ni];
        float e = __expf(2.f * x);
        s += (1.f - 2.f / (e + 1.f)) * vv[ni];
      }
      s += __shfl_xor(s, 1);
      s += __shfl_xor(s, 2);
      s += __shfl_xor(s, 4);
      s += __shfl_xor(s, 8);
      if (li == 0) atomicAdd(&scores[m0 + wm * 64 + mi * 16 + hi * 4 + r], s);
    }
  }
}

// ---- softmax over S per batch; bv cancels ----
__global__ void k_softmax(const float* __restrict__ scores, float* __restrict__ wts) {
  __shared__ float red[8];
  int b = blockIdx.x;
  int t = threadIdx.x;
  float v[8];
  float mx = -3.4e38f;
#pragma unroll
  for (int i = 0; i < 8; ++i) {
    v[i] = scores[b * SEQ + i * 256 + t];
    mx = fmaxf(mx, v[i]);
  }
#pragma unroll
  for (int o = 1; o < 64; o <<= 1) mx = fmaxf(mx, __shfl_xor(mx, o));
  if ((t & 63) == 0) red[t >> 6] = mx;
  __syncthreads();
  mx = fmaxf(fmaxf(red[0], red[1]), fmaxf(red[2], red[3]));
  float sum = 0.f;
#pragma unroll
  for (int i = 0; i < 8; ++i) { v[i] = __expf(v[i] - mx); sum += v[i]; }
#pragma unroll
  for (int o = 1; o < 64; o <<= 1) sum += __shfl_xor(sum, o);
  if ((t & 63) == 0) red[4 + (t >> 6)] = sum;
  __syncthreads();
  float inv = 1.f / (red[4] + red[5] + red[6] + red[7]);
#pragma unroll
  for (int i = 0; i < 8; ++i) wts[b * SEQ + i * 256 + t] = v[i] * inv;
}

// ---- context from fp32 values (vectorized): ctx[b][h]=sum_s w*v ----
__global__ void k_context_f32v(const float* __restrict__ values,
                               const float* __restrict__ wts, float* __restrict__ ctx) {
  int b = blockIdx.x, sc = blockIdx.y;
  int h4 = threadIdx.x * 4;
  const float* vb = values + (size_t)b * SEQ * H;
  float a0 = 0, a1 = 0, a2 = 0, a3 = 0;
  int s0 = sc * 64;
#pragma unroll 4
  for (int s = s0; s < s0 + 64; ++s) {
    float w = wts[b * SEQ + s];
    float4 v = *reinterpret_cast<const float4*>(&vb[(size_t)s * H + h4]);
    a0 = fmaf(w, v.x, a0);
    a1 = fmaf(w, v.y, a1);
    a2 = fmaf(w, v.z, a2);
    a3 = fmaf(w, v.w, a3);
  }
  atomicAdd(&ctx[b * H + h4 + 0], a0);
  atomicAdd(&ctx[b * H + h4 + 1], a1);
  atomicAdd(&ctx[b * H + h4 + 2], a2);
  atomicAdd(&ctx[b * H + h4 + 3], a3);
}

// ---- fp32 context (fallback path) ----
__global__ void k_context(const float* __restrict__ values, const float* __restrict__ wts,
                          float* __restrict__ ctx) {
  int b = blockIdx.x, hc = blockIdx.y, sc = blockIdx.z;
  int h = hc * 256 + threadIdx.x;
  const float* vb = values + (size_t)b * SEQ * H;
  float acc = 0.f;
  int s0 = sc * 128;
#pragma unroll 4
  for (int s = s0; s < s0 + 128; ++s)
    acc = fmaf(wts[b * SEQ + s], vb[(size_t)s * H + h], acc);
  atomicAdd(&ctx[b * H + h], acc);
}

extern "C" void kernel_launch(void* const* d_in, const int* in_sizes, int n_in,
                              void* d_out, int out_size, void* d_ws, size_t ws_size,
                              hipStream_t stream) {
  (void)in_sizes; (void)n_in; (void)out_size;
  const float* query  = (const float*)d_in[0];
  const float* values = (const float*)d_in[1];
  const float* W1     = (const float*)d_in[2];
  const float* b1     = (const float*)d_in[3];
  const float* W2     = (const float*)d_in[4];
  const float* b2     = (const float*)d_in[5];
  const float* V      = (const float*)d_in[6];
  // d_in[7] = bv: cancels in softmax -> unused.

  float* out = (float*)d_out;
  float* ctx = out;             // [32][1024]
  float* wts = out + BATCH * H; // [32][2048]

  const size_t need = (2u << 20) + (256u << 10) + (128u << 10);  // W1T+scores+projq

  if (ws_size >= need) {
    char* ws = (char*)d_ws;
    unsigned short* W1T = (unsigned short*)ws;                   // 2 MB
    float* scores = (float*)(ws + (2u << 20));                   // 256 KB
    float* projq  = (float*)(ws + (2u << 20) + (256u << 10));    // 128 KB

    k_prep2<<<1184, 256, 0, stream>>>(W1, W1T, query, W2, b2, projq, scores, ctx);
    k_score4<<<(M_TOT / BM) * (UNITS / BN), 512, 0, stream>>>(values, W1T, b1, projq, V, scores);
    k_softmax<<<BATCH, 256, 0, stream>>>(scores, wts);
    k_context_f32v<<<dim3(BATCH, 32), 256, 0, stream>>>(values, wts, ctx);
  } else {
    char* ws = (char*)d_ws;
    unsigned short* W1T = (unsigned short*)ws;
    float* scores = (float*)(ws + (2u << 20));
    float* projq  = (float*)(ws + (2u << 20) + (256u << 10));

    hipMemsetAsync(scores, 0, M_TOT * sizeof(float), stream);
    hipMemsetAsync(ctx, 0, BATCH * H * sizeof(float), stream);

    k_transpose_w1<<<dim3(32, 32), dim3(32, 8), 0, stream>>>(W1, W1T);
    k_projq<<<dim3(32, 4), 256, 0, stream>>>(query, W2, b2, projq);
    k_score_f32<<<dim3(UNITS / FBN, M_TOT / FBM), 256, 0, stream>>>(values, W1T, b1, projq, V, scores);
    k_softmax<<<BATCH, 256, 0, stream>>>(scores, wts);
    k_context<<<dim3(BATCH, H / 256, 16), 256, 0, stream>>>(values, wts, ctx);
  }
}